// Round 8
// baseline (278.044 us; speedup 1.0000x reference)
//
#include <hip/hip_runtime.h>
#include <hip/hip_bf16.h>
#include <stdint.h>

#define B_    4
#define T_    2048
#define D_    1024
#define H_    16
#define HD_   64
#define ROWS_ (B_ * T_)      // 8192
#define NQKV_ (3 * D_)       // 3072

typedef __attribute__((ext_vector_type(8))) short bf16x8;
typedef __attribute__((ext_vector_type(4))) float f32x4;

__device__ __forceinline__ unsigned short f2bf(float f) {
    union { float f; uint32_t u; } v; v.f = f;
    uint32_t u = v.u;
    return (unsigned short)((u + 0x7FFFu + ((u >> 16) & 1u)) >> 16);  // RNE
}

// RTZ pack of two floats to bf16x2 (lo = a) in ONE v_perm_b32. Only used
// for P (softmax self-normalizes: osum uses the same bf16 P -> bias cancels).
__device__ __forceinline__ uint32_t pack2_rtz(float a, float b) {
    union { float f; uint32_t u; } x, y; x.f = a; y.f = b;
    return __builtin_amdgcn_perm(y.u, x.u, 0x07060302u);
}

__device__ __forceinline__ void glds16(const unsigned short* g, unsigned short* l) {
    __builtin_amdgcn_global_load_lds(
        (const __attribute__((address_space(1))) void*)g,
        (__attribute__((address_space(3))) void*)l, 16, 0, 0);
}

// ---------------- fp32 -> bf16 convert (plain) ----------------
__global__ void cvt_bf16_kernel(const float* __restrict__ in,
                                unsigned short* __restrict__ out, int n8) {
    int i = blockIdx.x * blockDim.x + threadIdx.x;
    if (i >= n8) return;
    float4 a = ((const float4*)in)[2 * i];
    float4 b = ((const float4*)in)[2 * i + 1];
    union { bf16x8 v; unsigned short s[8]; } o;
    o.s[0] = f2bf(a.x); o.s[1] = f2bf(a.y); o.s[2] = f2bf(a.z); o.s[3] = f2bf(a.w);
    o.s[4] = f2bf(b.x); o.s[5] = f2bf(b.y); o.s[6] = f2bf(b.z); o.s[7] = f2bf(b.w);
    ((bf16x8*)out)[i] = o.v;
}

// ---------------- fused weight transpose+convert ----------------
__global__ __launch_bounds__(256) void tcvt2_kernel(const float* __restrict__ wqkv,
                                                    const float* __restrict__ wout,
                                                    unsigned short* __restrict__ oqkv,
                                                    unsigned short* __restrict__ oout,
                                                    float scale) {
    __shared__ float tile[64 * 65];
    const int t = threadIdx.x;
    const bool second = blockIdx.x >= 48;
    const float* in = second ? wout : wqkv;
    unsigned short* out = second ? oout : oqkv;
    const int N = second ? 1024 : 3072;
    const int ncut = second ? 0 : 1024;
    const int n0 = (second ? (blockIdx.x - 48) : blockIdx.x) * 64;
    const int k0 = blockIdx.y * 64;
    const int K = 1024;
#pragma unroll
    for (int it = 0; it < 4; ++it) {
        int id = it * 256 + t;
        int r = id >> 4, c = (id & 15) * 4;
        float4 v = *(const float4*)&in[(size_t)(k0 + r) * N + n0 + c];
        tile[r * 65 + c + 0] = v.x; tile[r * 65 + c + 1] = v.y;
        tile[r * 65 + c + 2] = v.z; tile[r * 65 + c + 3] = v.w;
    }
    __syncthreads();
#pragma unroll
    for (int it = 0; it < 2; ++it) {
        int id = it * 256 + t;
        int n = id >> 3, kc = (id & 7) * 8;
        float sc = (n0 + n < ncut) ? scale : 1.0f;
        union { bf16x8 v; unsigned short s[8]; } o;
#pragma unroll
        for (int i = 0; i < 8; ++i) o.s[i] = f2bf(tile[(kc + i) * 65 + n] * sc);
        *(bf16x8*)&out[(size_t)(n0 + n) * K + k0 + kc] = o.v;
    }
}

// ---------------- GEMM: C[M,N] = A[M,K] * Bt[N,K]^T ----------------
// 128x128 tile, BK=64, XOR-swizzled LDS chunks, glds width-16 staging.
template<int OUT_BF16, int VSPLIT>
__global__ __launch_bounds__(256) void gemm128_kernel(
    const unsigned short* __restrict__ A,
    const unsigned short* __restrict__ Bt,
    void* __restrict__ Cp, int M, int K, int ldC,
    unsigned short* __restrict__ vt)
{
    __shared__ __align__(16) unsigned short As[128 * 64];
    __shared__ __align__(16) unsigned short Bs[128 * 64];

    const int t = threadIdx.x, w = t >> 6, lane = t & 63;
    const int wm = w >> 1, wn = w & 1;
    const int lm = lane & 15, lq = lane >> 4;
    const int m0 = blockIdx.y * 128, n0 = blockIdx.x * 128;

    f32x4 acc[4][4];
#pragma unroll
    for (int i = 0; i < 4; i++)
#pragma unroll
        for (int j = 0; j < 4; j++) acc[i][j] = (f32x4){0.f, 0.f, 0.f, 0.f};

    const unsigned short* Ap[4];
    const unsigned short* Bp[4];
#pragma unroll
    for (int s = 0; s < 4; s++) {
        int id = s * 256 + t;
        int row = id >> 3, gch = (id & 7) ^ (row & 7);
        Ap[s] = A  + (size_t)(m0 + row) * K + gch * 8;
        Bp[s] = Bt + (size_t)(n0 + row) * K + gch * 8;
    }

    for (int k0 = 0; k0 < K; k0 += 64) {
        __syncthreads();
#pragma unroll
        for (int s = 0; s < 4; s++) glds16(Ap[s] + k0, &As[(s * 256 + t) * 8]);
#pragma unroll
        for (int s = 0; s < 4; s++) glds16(Bp[s] + k0, &Bs[(s * 256 + t) * 8]);
        __syncthreads();

#pragma unroll
        for (int kh = 0; kh < 2; kh++) {
            bf16x8 af[4], bfr[4];
#pragma unroll
            for (int mt = 0; mt < 4; mt++) {
                int row = wm * 64 + mt * 16 + lm;
                int sch = (kh * 4 + lq) ^ (lm & 7);
                af[mt] = *(const bf16x8*)&As[row * 64 + sch * 8];
            }
#pragma unroll
            for (int nt = 0; nt < 4; nt++) {
                int row = wn * 64 + nt * 16 + lm;
                int sch = (kh * 4 + lq) ^ (lm & 7);
                bfr[nt] = *(const bf16x8*)&Bs[row * 64 + sch * 8];
            }
#pragma unroll
            for (int mt = 0; mt < 4; mt++)
#pragma unroll
                for (int nt = 0; nt < 4; nt++)
                    acc[mt][nt] = __builtin_amdgcn_mfma_f32_16x16x32_bf16(
                        af[mt], bfr[nt], acc[mt][nt], 0, 0, 0);
        }
    }

    if (VSPLIT && n0 >= 2048) {
#pragma unroll
        for (int mt = 0; mt < 4; mt++)
#pragma unroll
            for (int nt = 0; nt < 4; nt++) {
                int row0 = m0 + wm * 64 + mt * 16 + lq * 4;
                int col  = n0 + wn * 64 + nt * 16 + lm - 2048;
                int bb = row0 >> 11, tt = row0 & 2047;
                size_t vi = ((size_t)((bb * 16 + (col >> 6)) * 64 + (col & 63))) * 2048 + tt;
                uint2 pk;
                pk.x = pack2_rtz(0.f, 0.f);  // placate compiler? no—real pack below
                pk.x = (uint32_t)f2bf(acc[mt][nt][0]) | ((uint32_t)f2bf(acc[mt][nt][1]) << 16);
                pk.y = (uint32_t)f2bf(acc[mt][nt][2]) | ((uint32_t)f2bf(acc[mt][nt][3]) << 16);
                *(uint2*)&vt[vi] = pk;
            }
        return;
    }
#pragma unroll
    for (int mt = 0; mt < 4; mt++)
#pragma unroll
        for (int nt = 0; nt < 4; nt++)
#pragma unroll
            for (int r = 0; r < 4; r++) {
                int row = m0 + wm * 64 + mt * 16 + lq * 4 + r;
                int col = n0 + wn * 64 + nt * 16 + lm;
                if (OUT_BF16)
                    ((unsigned short*)Cp)[(size_t)row * ldC + col] = f2bf(acc[mt][nt][r]);
                else
                    ((float*)Cp)[(size_t)row * ldC + col] = acc[mt][nt][r];
            }
}

// ---- one 32q x 64k attention tile step (S^T MFMA -> exp2 -> P -> PV) ----
__device__ __forceinline__ void attn_step(
    int kt, int qw0, const bf16x8 (&qf)[2][2],
    f32x4 (&o)[2][4], f32x4 (&osum)[2],
    const unsigned short* Ks, const unsigned short* Vs,
    unsigned short* psw, int lm, int lq, bf16x8 onesf)
{
    // S^T = K Q^T: lane holds (row=key=lq*4+r, col=query=lm)
    f32x4 st[4][2];
#pragma unroll
    for (int nt = 0; nt < 4; nt++)
#pragma unroll
        for (int mt = 0; mt < 2; mt++) st[nt][mt] = (f32x4){0.f, 0.f, 0.f, 0.f};
#pragma unroll
    for (int nt = 0; nt < 4; nt++)
#pragma unroll
        for (int kk = 0; kk < 2; kk++) {
            bf16x8 kf = *(const bf16x8*)
                &Ks[(nt * 16 + lm) * 64 + ((kk * 4 + lq) ^ (lm & 7)) * 8];
#pragma unroll
            for (int mt = 0; mt < 2; mt++)
                st[nt][mt] = __builtin_amdgcn_mfma_f32_16x16x32_bf16(
                    kf, qf[mt][kk], st[nt][mt], 0, 0, 0);
        }

    // p = exp2(s) (mask only diagonal tiles), pack 4 -> b64 store
    const bool diag = (kt + 64 > qw0);
#pragma unroll
    for (int mt = 0; mt < 2; mt++) {
        const int qi = qw0 + mt * 16 + lm;
#pragma unroll
        for (int nt = 0; nt < 4; nt++) {
            float p[4];
            if (diag) {
                const int kj0 = kt + nt * 16 + lq * 4;
#pragma unroll
                for (int r = 0; r < 4; r++)
                    p[r] = (kj0 + r <= qi)
                         ? __builtin_amdgcn_exp2f(st[nt][mt][r]) : 0.f;
            } else {
#pragma unroll
                for (int r = 0; r < 4; r++)
                    p[r] = __builtin_amdgcn_exp2f(st[nt][mt][r]);
            }
            uint2 pk;
            pk.x = pack2_rtz(p[0], p[1]);
            pk.y = pack2_rtz(p[2], p[3]);
            *(uint2*)&psw[(mt * 16 + lm) * 72 + nt * 16 + lq * 4] = pk;
        }
    }

    // PV (16 MFMAs) + row-sum via ones-MFMA (4 MFMAs)
#pragma unroll
    for (int kk = 0; kk < 2; kk++) {
        bf16x8 pf0 = *(const bf16x8*)&psw[(lm) * 72 + kk * 32 + lq * 8];
        bf16x8 pf1 = *(const bf16x8*)&psw[(16 + lm) * 72 + kk * 32 + lq * 8];
        osum[0] = __builtin_amdgcn_mfma_f32_16x16x32_bf16(pf0, onesf, osum[0], 0, 0, 0);
        osum[1] = __builtin_amdgcn_mfma_f32_16x16x32_bf16(pf1, onesf, osum[1], 0, 0, 0);
#pragma unroll
        for (int dt = 0; dt < 4; dt++) {
            bf16x8 vf = *(const bf16x8*)
                &Vs[(dt * 16 + lm) * 64 + ((kk * 4 + lq) ^ (lm & 7)) * 8];
            o[0][dt] = __builtin_amdgcn_mfma_f32_16x16x32_bf16(pf0, vf, o[0][dt], 0, 0, 0);
            o[1][dt] = __builtin_amdgcn_mfma_f32_16x16x32_bf16(pf1, vf, o[1][dt], 0, 0, 0);
        }
    }
}

// ---------------- fused causal flash attention v7 ----------------
// v4 grid/locality (x=bh, y=pair, 512 blocks) + XOR-swizzled K/V staging +
// MERGED pair loop: block (bh,p) owns qt {15-p, p}; each K/V tile is staged
// once and consumed by both q-tiles while in causal range. Register prefetch
// of next tile hides global latency across the compute.
__global__ __launch_bounds__(256) void attn7_kernel(
    const unsigned short* __restrict__ qk,
    const unsigned short* __restrict__ vt,
    unsigned short* __restrict__ y)
{
    __shared__ __align__(16) unsigned short Ks[64 * 64];   // [key][d], XOR swizzle
    __shared__ __align__(16) unsigned short Vs[64 * 64];   // [d][key], XOR swizzle
    __shared__ __align__(16) unsigned short Ps[4][32 * 72];

    const int bh = blockIdx.x, p = blockIdx.y;     // x=bh-major dispatch (v4 locality)
    const int b = bh >> 4, h = bh & 15;
    const int t = threadIdx.x, w = t >> 6, lane = t & 63;
    const int lm = lane & 15, lq = lane >> 4;
    unsigned short* psw = Ps[w];

    const int r0 = t >> 3, r1 = r0 + 32, gc = (t & 7) * 8;
    const int xc0 = ((t & 7) ^ (r0 & 7)) * 8;
    const int xc1 = ((t & 7) ^ (r1 & 7)) * 8;
    const unsigned short* kgb = qk + (size_t)(b * T_) * 2048 + D_ + h * HD_;
    const unsigned short* vgb = vt + (size_t)(bh * 64) * 2048;

    const bf16x8 onesf = {0x3F80, 0x3F80, 0x3F80, 0x3F80,
                          0x3F80, 0x3F80, 0x3F80, 0x3F80};  // bf16 1.0 x8

    const int qtb = 15 - p, qts = p;               // big + small q-tiles
    const int q0b = qtb * 128, qw0b = q0b + w * 32;
    const int q0s = qts * 128, qw0s = q0s + w * 32;
    const int kendb = q0b + 128, kends = q0s + 128;

    // Q fragments for both tiles: lane holds Q[q=lm][d=lq*8+j]
    bf16x8 qfb[2][2], qfs[2][2];
#pragma unroll
    for (int mt = 0; mt < 2; mt++)
#pragma unroll
        for (int kk = 0; kk < 2; kk++) {
            qfb[mt][kk] = *(const bf16x8*)
                &qk[(size_t)(b * T_ + qw0b + mt * 16 + lm) * 2048 + h * HD_ + kk * 32 + lq * 8];
            qfs[mt][kk] = *(const bf16x8*)
                &qk[(size_t)(b * T_ + qw0s + mt * 16 + lm) * 2048 + h * HD_ + kk * 32 + lq * 8];
        }

    f32x4 ob[2][4], osumb[2], os_[2][4], osums[2];
#pragma unroll
    for (int mt = 0; mt < 2; mt++) {
        osumb[mt] = (f32x4){0.f, 0.f, 0.f, 0.f};
        osums[mt] = (f32x4){0.f, 0.f, 0.f, 0.f};
#pragma unroll
        for (int dt = 0; dt < 4; dt++) {
            ob[mt][dt] = (f32x4){0.f, 0.f, 0.f, 0.f};
            os_[mt][dt] = (f32x4){0.f, 0.f, 0.f, 0.f};
        }
    }

    // prefetch tile 0 into registers
    bf16x8 ka = *(const bf16x8*)&kgb[(size_t)r0 * 2048 + gc];
    bf16x8 kb = *(const bf16x8*)&kgb[(size_t)r1 * 2048 + gc];
    bf16x8 va = *(const bf16x8*)&vgb[(size_t)r0 * 2048 + gc];
    bf16x8 vb = *(const bf16x8*)&vgb[(size_t)r1 * 2048 + gc];

    for (int kt = 0; kt < kendb; kt += 64) {
        __syncthreads();               // previous tile fully consumed
        *(bf16x8*)&Ks[r0 * 64 + xc0] = ka;
        *(bf16x8*)&Ks[r1 * 64 + xc1] = kb;
        *(bf16x8*)&Vs[r0 * 64 + xc0] = va;
        *(bf16x8*)&Vs[r1 * 64 + xc1] = vb;
        // prefetch next tile (redundant reload on last iter)
        int ktn = (kt + 64 < kendb) ? kt + 64 : kt;
        ka = *(const bf16x8*)&kgb[(size_t)(ktn + r0) * 2048 + gc];
        kb = *(const bf16x8*)&kgb[(size_t)(ktn + r1) * 2048 + gc];
        va = *(const bf16x8*)&vgb[(size_t)r0 * 2048 + ktn + gc];
        vb = *(const bf16x8*)&vgb[(size_t)r1 * 2048 + ktn + gc];
        __syncthreads();

        if (kt < qw0b + 32)                       // big tile in causal range
            attn_step(kt, qw0b, qfb, ob, osumb, Ks, Vs, psw, lm, lq, onesf);
        if (kt < kends && kt < qw0s + 32)         // small tile in range
            attn_step(kt, qw0s, qfs, os_, osums, Ks, Vs, psw, lm, lq, onesf);
    }

    // epilogue: both q-tiles
#pragma unroll
    for (int mt = 0; mt < 2; mt++)
#pragma unroll
        for (int r = 0; r < 4; r++) {
            float rlb = 1.f / osumb[mt][r];
            float rls = 1.f / osums[mt][r];
#pragma unroll
            for (int dt = 0; dt < 4; dt++) {
                y[(size_t)(b * T_ + qw0b + mt * 16 + lq * 4 + r) * D_ + h * HD_ + dt * 16 + lm]
                    = f2bf(ob[mt][dt][r] * rlb);
                y[(size_t)(b * T_ + qw0s + mt * 16 + lq * 4 + r) * D_ + h * HD_ + dt * 16 + lm]
                    = f2bf(os_[mt][dt][r] * rls);
            }
        }
}

// ---------------- launch ----------------
extern "C" void kernel_launch(void* const* d_in, const int* in_sizes, int n_in,
                              void* d_out, int out_size, void* d_ws, size_t ws_size,
                              hipStream_t stream) {
    const float* x    = (const float*)d_in[0];
    const float* wqkv = (const float*)d_in[1];
    const float* wout = (const float*)d_in[2];
    float* out = (float*)d_out;

    char* ws = (char*)d_ws;
    unsigned short* xb     = (unsigned short*)ws; ws += (size_t)ROWS_ * D_ * 2;
    unsigned short* wqkvbt = (unsigned short*)ws; ws += (size_t)D_ * NQKV_ * 2;
    unsigned short* woutbt = (unsigned short*)ws; ws += (size_t)D_ * D_ * 2;
    unsigned short* qkb    = (unsigned short*)ws; ws += (size_t)ROWS_ * 2048 * 2;
    unsigned short* vtb    = (unsigned short*)ws; ws += (size_t)ROWS_ * D_ * 2;
    unsigned short* yb     = (unsigned short*)ws;

    const float SC = 0.18033688011112042f;  // 0.125 * log2(e): softmax in exp2 domain

    cvt_bf16_kernel<<<ROWS_ * D_ / 8 / 256, 256, 0, stream>>>(x, xb, ROWS_ * D_ / 8);
    tcvt2_kernel<<<dim3(64, 16), 256, 0, stream>>>(wqkv, wout, wqkvbt, woutbt, SC);

    gemm128_kernel<1, 1><<<dim3(NQKV_ / 128, ROWS_ / 128), 256, 0, stream>>>(
        xb, wqkvbt, qkb, ROWS_, D_, 2048, vtb);

    attn7_kernel<<<dim3(B_ * H_, 8), 256, 0, stream>>>(qkb, vtb, yb);

    gemm128_kernel<0, 0><<<dim3(D_ / 128, ROWS_ / 128), 256, 0, stream>>>(
        yb, woutbt, out, ROWS_, D_, D_, nullptr);
}

// Round 9
// 245.129 us; speedup vs baseline: 1.1343x; 1.1343x over previous
//
#include <hip/hip_runtime.h>
#include <hip/hip_bf16.h>
#include <stdint.h>

#define B_    4
#define T_    2048
#define D_    1024
#define H_    16
#define HD_   64
#define ROWS_ (B_ * T_)      // 8192
#define NQKV_ (3 * D_)       // 3072

typedef __attribute__((ext_vector_type(8))) short bf16x8;
typedef __attribute__((ext_vector_type(4))) float f32x4;

__device__ __forceinline__ unsigned short f2bf(float f) {
    union { float f; uint32_t u; } v; v.f = f;
    uint32_t u = v.u;
    return (unsigned short)((u + 0x7FFFu + ((u >> 16) & 1u)) >> 16);  // RNE
}

// RTZ pack of two floats to bf16x2 (lo = a) in ONE v_perm_b32. Only used
// for P (softmax self-normalizes: osum uses the same bf16 P -> bias cancels).
__device__ __forceinline__ uint32_t pack2_rtz(float a, float b) {
    union { float f; uint32_t u; } x, y; x.f = a; y.f = b;
    return __builtin_amdgcn_perm(y.u, x.u, 0x07060302u);
}

__device__ __forceinline__ void glds16(const unsigned short* g, unsigned short* l) {
    __builtin_amdgcn_global_load_lds(
        (const __attribute__((address_space(1))) void*)g,
        (__attribute__((address_space(3))) void*)l, 16, 0, 0);
}

// ---------------- fp32 -> bf16 convert (plain) ----------------
__global__ void cvt_bf16_kernel(const float* __restrict__ in,
                                unsigned short* __restrict__ out, int n8) {
    int i = blockIdx.x * blockDim.x + threadIdx.x;
    if (i >= n8) return;
    float4 a = ((const float4*)in)[2 * i];
    float4 b = ((const float4*)in)[2 * i + 1];
    union { bf16x8 v; unsigned short s[8]; } o;
    o.s[0] = f2bf(a.x); o.s[1] = f2bf(a.y); o.s[2] = f2bf(a.z); o.s[3] = f2bf(a.w);
    o.s[4] = f2bf(b.x); o.s[5] = f2bf(b.y); o.s[6] = f2bf(b.z); o.s[7] = f2bf(b.w);
    ((bf16x8*)out)[i] = o.v;
}

// ---------------- fused weight transpose+convert ----------------
__global__ __launch_bounds__(256) void tcvt2_kernel(const float* __restrict__ wqkv,
                                                    const float* __restrict__ wout,
                                                    unsigned short* __restrict__ oqkv,
                                                    unsigned short* __restrict__ oout,
                                                    float scale) {
    __shared__ float tile[64 * 65];
    const int t = threadIdx.x;
    const bool second = blockIdx.x >= 48;
    const float* in = second ? wout : wqkv;
    unsigned short* out = second ? oout : oqkv;
    const int N = second ? 1024 : 3072;
    const int ncut = second ? 0 : 1024;
    const int n0 = (second ? (blockIdx.x - 48) : blockIdx.x) * 64;
    const int k0 = blockIdx.y * 64;
    const int K = 1024;
#pragma unroll
    for (int it = 0; it < 4; ++it) {
        int id = it * 256 + t;
        int r = id >> 4, c = (id & 15) * 4;
        float4 v = *(const float4*)&in[(size_t)(k0 + r) * N + n0 + c];
        tile[r * 65 + c + 0] = v.x; tile[r * 65 + c + 1] = v.y;
        tile[r * 65 + c + 2] = v.z; tile[r * 65 + c + 3] = v.w;
    }
    __syncthreads();
#pragma unroll
    for (int it = 0; it < 2; ++it) {
        int id = it * 256 + t;
        int n = id >> 3, kc = (id & 7) * 8;
        float sc = (n0 + n < ncut) ? scale : 1.0f;
        union { bf16x8 v; unsigned short s[8]; } o;
#pragma unroll
        for (int i = 0; i < 8; ++i) o.s[i] = f2bf(tile[(kc + i) * 65 + n] * sc);
        *(bf16x8*)&out[(size_t)(n0 + n) * K + k0 + kc] = o.v;
    }
}

// ---------------- GEMM: C[M,N] = A[M,K] * Bt[N,K]^T ----------------
// 128x128 tile, BK=64, XOR-swizzled LDS chunks, glds width-16 staging.
template<int OUT_BF16, int VSPLIT>
__global__ __launch_bounds__(256) void gemm128_kernel(
    const unsigned short* __restrict__ A,
    const unsigned short* __restrict__ Bt,
    void* __restrict__ Cp, int M, int K, int ldC,
    unsigned short* __restrict__ vt)
{
    __shared__ __align__(16) unsigned short As[128 * 64];
    __shared__ __align__(16) unsigned short Bs[128 * 64];

    const int t = threadIdx.x, w = t >> 6, lane = t & 63;
    const int wm = w >> 1, wn = w & 1;
    const int lm = lane & 15, lq = lane >> 4;
    const int m0 = blockIdx.y * 128, n0 = blockIdx.x * 128;

    f32x4 acc[4][4];
#pragma unroll
    for (int i = 0; i < 4; i++)
#pragma unroll
        for (int j = 0; j < 4; j++) acc[i][j] = (f32x4){0.f, 0.f, 0.f, 0.f};

    const unsigned short* Ap[4];
    const unsigned short* Bp[4];
#pragma unroll
    for (int s = 0; s < 4; s++) {
        int id = s * 256 + t;
        int row = id >> 3, gch = (id & 7) ^ (row & 7);
        Ap[s] = A  + (size_t)(m0 + row) * K + gch * 8;
        Bp[s] = Bt + (size_t)(n0 + row) * K + gch * 8;
    }

    for (int k0 = 0; k0 < K; k0 += 64) {
        __syncthreads();
#pragma unroll
        for (int s = 0; s < 4; s++) glds16(Ap[s] + k0, &As[(s * 256 + t) * 8]);
#pragma unroll
        for (int s = 0; s < 4; s++) glds16(Bp[s] + k0, &Bs[(s * 256 + t) * 8]);
        __syncthreads();

#pragma unroll
        for (int kh = 0; kh < 2; kh++) {
            bf16x8 af[4], bfr[4];
#pragma unroll
            for (int mt = 0; mt < 4; mt++) {
                int row = wm * 64 + mt * 16 + lm;
                int sch = (kh * 4 + lq) ^ (lm & 7);
                af[mt] = *(const bf16x8*)&As[row * 64 + sch * 8];
            }
#pragma unroll
            for (int nt = 0; nt < 4; nt++) {
                int row = wn * 64 + nt * 16 + lm;
                int sch = (kh * 4 + lq) ^ (lm & 7);
                bfr[nt] = *(const bf16x8*)&Bs[row * 64 + sch * 8];
            }
#pragma unroll
            for (int mt = 0; mt < 4; mt++)
#pragma unroll
                for (int nt = 0; nt < 4; nt++)
                    acc[mt][nt] = __builtin_amdgcn_mfma_f32_16x16x32_bf16(
                        af[mt], bfr[nt], acc[mt][nt], 0, 0, 0);
        }
    }

    if (VSPLIT && n0 >= 2048) {
#pragma unroll
        for (int mt = 0; mt < 4; mt++)
#pragma unroll
            for (int nt = 0; nt < 4; nt++) {
                int row0 = m0 + wm * 64 + mt * 16 + lq * 4;
                int col  = n0 + wn * 64 + nt * 16 + lm - 2048;
                int bb = row0 >> 11, tt = row0 & 2047;
                size_t vi = ((size_t)((bb * 16 + (col >> 6)) * 64 + (col & 63))) * 2048 + tt;
                uint2 pk;
                pk.x = (uint32_t)f2bf(acc[mt][nt][0]) | ((uint32_t)f2bf(acc[mt][nt][1]) << 16);
                pk.y = (uint32_t)f2bf(acc[mt][nt][2]) | ((uint32_t)f2bf(acc[mt][nt][3]) << 16);
                *(uint2*)&vt[vi] = pk;
            }
        return;
    }
#pragma unroll
    for (int mt = 0; mt < 4; mt++)
#pragma unroll
        for (int nt = 0; nt < 4; nt++)
#pragma unroll
            for (int r = 0; r < 4; r++) {
                int row = m0 + wm * 64 + mt * 16 + lq * 4 + r;
                int col = n0 + wn * 64 + nt * 16 + lm;
                if (OUT_BF16)
                    ((unsigned short*)Cp)[(size_t)row * ldC + col] = f2bf(acc[mt][nt][r]);
                else
                    ((float*)Cp)[(size_t)row * ldC + col] = acc[mt][nt][r];
            }
}

// ---------------- fused causal flash attention v8 ----------------
// EXACT round-5 (attn4) structure: grid (x=bh, y=pair of qt {15-p, p}),
// 4 waves x 32q, 64-key tiles, register prefetch of next K/V tile, max-free
// softmax, S^T operand swap, ones-MFMA row sums. Only changes vs r5:
//   - Ks/Vs are unpadded stride-64 with XOR chunk swizzle (conflict-free
//     staging stores, 2-way frag reads; r7/r8 measured 7.57e6 -> 3.24e6)
//   - pack2_rtz is a single v_perm_b32
__global__ __launch_bounds__(256) void attn8_kernel(
    const unsigned short* __restrict__ qk,
    const unsigned short* __restrict__ vt,
    unsigned short* __restrict__ y)
{
    __shared__ __align__(16) unsigned short Ks[64 * 64];   // [key][d], XOR swizzle
    __shared__ __align__(16) unsigned short Vs[64 * 64];   // [d][key], XOR swizzle
    __shared__ __align__(16) unsigned short Ps[4][32 * 72];

    const int bh = blockIdx.x, pair = blockIdx.y;   // bh-major dispatch locality
    const int b = bh >> 4, h = bh & 15;
    const int t = threadIdx.x, w = t >> 6, lane = t & 63;
    const int lm = lane & 15, lq = lane >> 4;
    unsigned short* psw = Ps[w];

    const int r0 = t >> 3, r1 = r0 + 32, gc = (t & 7) * 8;
    const int xc0 = ((t & 7) ^ (r0 & 7)) * 8;
    const int xc1 = ((t & 7) ^ (r1 & 7)) * 8;
    const unsigned short* kgb = qk + (size_t)(b * T_) * 2048 + D_ + h * HD_;
    const unsigned short* vgb = vt + (size_t)(bh * 64) * 2048;

    const bf16x8 onesf = {0x3F80, 0x3F80, 0x3F80, 0x3F80,
                          0x3F80, 0x3F80, 0x3F80, 0x3F80};  // bf16 1.0 x8

    for (int which = 0; which < 2; ++which) {
        const int qt = which ? pair : (15 - pair);   // big tile first
        const int q0 = qt * 128, qw0 = q0 + w * 32;

        // Q fragments (B-operand): lane holds Q[q=lm][d=lq*8+j]
        bf16x8 qf[2][2];
#pragma unroll
        for (int mt = 0; mt < 2; mt++)
#pragma unroll
            for (int kk = 0; kk < 2; kk++)
                qf[mt][kk] = *(const bf16x8*)
                    &qk[(size_t)(b * T_ + qw0 + mt * 16 + lm) * 2048 + h * HD_ + kk * 32 + lq * 8];

        f32x4 o[2][4], osum[2];
#pragma unroll
        for (int mt = 0; mt < 2; mt++) {
            osum[mt] = (f32x4){0.f, 0.f, 0.f, 0.f};
#pragma unroll
            for (int dt = 0; dt < 4; dt++) o[mt][dt] = (f32x4){0.f, 0.f, 0.f, 0.f};
        }

        const int kend = q0 + 128;

        // prefetch tile 0 into registers
        bf16x8 ka = *(const bf16x8*)&kgb[(size_t)r0 * 2048 + gc];
        bf16x8 kb = *(const bf16x8*)&kgb[(size_t)r1 * 2048 + gc];
        bf16x8 va = *(const bf16x8*)&vgb[(size_t)r0 * 2048 + gc];
        bf16x8 vb = *(const bf16x8*)&vgb[(size_t)r1 * 2048 + gc];

        for (int kt = 0; kt < kend; kt += 64) {
            __syncthreads();               // previous tile's compute done
            *(bf16x8*)&Ks[r0 * 64 + xc0] = ka;
            *(bf16x8*)&Ks[r1 * 64 + xc1] = kb;
            *(bf16x8*)&Vs[r0 * 64 + xc0] = va;
            *(bf16x8*)&Vs[r1 * 64 + xc1] = vb;
            // prefetch next tile (redundant reload of same tile on last iter)
            int ktn = (kt + 64 < kend) ? kt + 64 : kt;
            ka = *(const bf16x8*)&kgb[(size_t)(ktn + r0) * 2048 + gc];
            kb = *(const bf16x8*)&kgb[(size_t)(ktn + r1) * 2048 + gc];
            va = *(const bf16x8*)&vgb[(size_t)r0 * 2048 + ktn + gc];
            vb = *(const bf16x8*)&vgb[(size_t)r1 * 2048 + ktn + gc];
            __syncthreads();
            if (kt >= qw0 + 32) continue;  // fully masked for this wave

            // S^T = K Q^T: lane holds (row=key=lq*4+r, col=query=lm)
            f32x4 st[4][2];
#pragma unroll
            for (int nt = 0; nt < 4; nt++)
#pragma unroll
                for (int mt = 0; mt < 2; mt++) st[nt][mt] = (f32x4){0.f, 0.f, 0.f, 0.f};
#pragma unroll
            for (int nt = 0; nt < 4; nt++)
#pragma unroll
                for (int kk = 0; kk < 2; kk++) {
                    bf16x8 kf = *(const bf16x8*)
                        &Ks[(nt * 16 + lm) * 64 + ((kk * 4 + lq) ^ (lm & 7)) * 8];
#pragma unroll
                    for (int mt = 0; mt < 2; mt++)
                        st[nt][mt] = __builtin_amdgcn_mfma_f32_16x16x32_bf16(
                            kf, qf[mt][kk], st[nt][mt], 0, 0, 0);
                }

            // p = exp2(s) (mask only diagonal tiles), pack 4 -> b64 store
            const bool diag = (kt + 64 > qw0);
#pragma unroll
            for (int mt = 0; mt < 2; mt++) {
                const int qi = qw0 + mt * 16 + lm;
#pragma unroll
                for (int nt = 0; nt < 4; nt++) {
                    float p[4];
                    if (diag) {
                        const int kj0 = kt + nt * 16 + lq * 4;
#pragma unroll
                        for (int r = 0; r < 4; r++)
                            p[r] = (kj0 + r <= qi)
                                 ? __builtin_amdgcn_exp2f(st[nt][mt][r]) : 0.f;
                    } else {
#pragma unroll
                        for (int r = 0; r < 4; r++)
                            p[r] = __builtin_amdgcn_exp2f(st[nt][mt][r]);
                    }
                    uint2 pk;
                    pk.x = pack2_rtz(p[0], p[1]);
                    pk.y = pack2_rtz(p[2], p[3]);
                    *(uint2*)&psw[(mt * 16 + lm) * 72 + nt * 16 + lq * 4] = pk;
                }
            }

            // PV (16 MFMAs) + row-sum via ones-MFMA (4 MFMAs)
#pragma unroll
            for (int kk = 0; kk < 2; kk++) {
                bf16x8 pf0 = *(const bf16x8*)&psw[(lm) * 72 + kk * 32 + lq * 8];
                bf16x8 pf1 = *(const bf16x8*)&psw[(16 + lm) * 72 + kk * 32 + lq * 8];
                osum[0] = __builtin_amdgcn_mfma_f32_16x16x32_bf16(pf0, onesf, osum[0], 0, 0, 0);
                osum[1] = __builtin_amdgcn_mfma_f32_16x16x32_bf16(pf1, onesf, osum[1], 0, 0, 0);
#pragma unroll
                for (int dt = 0; dt < 4; dt++) {
                    bf16x8 vf = *(const bf16x8*)
                        &Vs[(dt * 16 + lm) * 64 + ((kk * 4 + lq) ^ (lm & 7)) * 8];
                    o[0][dt] = __builtin_amdgcn_mfma_f32_16x16x32_bf16(pf0, vf, o[0][dt], 0, 0, 0);
                    o[1][dt] = __builtin_amdgcn_mfma_f32_16x16x32_bf16(pf1, vf, o[1][dt], 0, 0, 0);
                }
            }
        }

#pragma unroll
        for (int mt = 0; mt < 2; mt++)
#pragma unroll
            for (int r = 0; r < 4; r++) {
                float rli = 1.f / osum[mt][r];
#pragma unroll
                for (int dt = 0; dt < 4; dt++)
                    y[(size_t)(b * T_ + qw0 + mt * 16 + lq * 4 + r) * D_ + h * HD_ + dt * 16 + lm]
                        = f2bf(o[mt][dt][r] * rli);
            }
    }
}

// ---------------- launch ----------------
extern "C" void kernel_launch(void* const* d_in, const int* in_sizes, int n_in,
                              void* d_out, int out_size, void* d_ws, size_t ws_size,
                              hipStream_t stream) {
    const float* x    = (const float*)d_in[0];
    const float* wqkv = (const float*)d_in[1];
    const float* wout = (const float*)d_in[2];
    float* out = (float*)d_out;

    char* ws = (char*)d_ws;
    unsigned short* xb     = (unsigned short*)ws; ws += (size_t)ROWS_ * D_ * 2;
    unsigned short* wqkvbt = (unsigned short*)ws; ws += (size_t)D_ * NQKV_ * 2;
    unsigned short* woutbt = (unsigned short*)ws; ws += (size_t)D_ * D_ * 2;
    unsigned short* qkb    = (unsigned short*)ws; ws += (size_t)ROWS_ * 2048 * 2;
    unsigned short* vtb    = (unsigned short*)ws; ws += (size_t)ROWS_ * D_ * 2;
    unsigned short* yb     = (unsigned short*)ws;

    const float SC = 0.18033688011112042f;  // 0.125 * log2(e): softmax in exp2 domain

    cvt_bf16_kernel<<<ROWS_ * D_ / 8 / 256, 256, 0, stream>>>(x, xb, ROWS_ * D_ / 8);
    tcvt2_kernel<<<dim3(64, 16), 256, 0, stream>>>(wqkv, wout, wqkvbt, woutbt, SC);

    gemm128_kernel<1, 1><<<dim3(NQKV_ / 128, ROWS_ / 128), 256, 0, stream>>>(
        xb, wqkvbt, qkb, ROWS_, D_, 2048, vtb);

    attn8_kernel<<<dim3(B_ * H_, 8), 256, 0, stream>>>(qkb, vtb, yb);

    gemm128_kernel<0, 0><<<dim3(D_ / 128, ROWS_ / 128), 256, 0, stream>>>(
        yb, woutbt, out, ROWS_, D_, D_, nullptr);
}